// Round 11
// baseline (7498.388 us; speedup 1.0000x reference)
//
#include <hip/hip_runtime.h>
#include <hip/hip_bf16.h>

#define SEQT 2000
#define NB   2048
#define H1   51
#define MROW 16
#define NBLK (NB / MROW)   // 128 blocks, one wave each
#define PAD  264           // shorts per staged row (528 B, 16B-aligned)

typedef float f32x4 __attribute__((ext_vector_type(4)));
typedef short s16x8 __attribute__((ext_vector_type(8)));

__device__ __forceinline__ short f2bf(float f) { __hip_bfloat16 b(f); return *(short*)&b; }
__device__ __forceinline__ float bf2f(short s) { __hip_bfloat16 b; *(short*)&b = s; return (float)b; }
__device__ __forceinline__ float rbf(float f) { return bf2f(f2bf(f)); }
__device__ __forceinline__ float sigf(float x) { return 1.f / (1.f + __expf(-x)); }
__device__ __forceinline__ float tanhfast(float x) { return 1.f - 2.f / (__expf(2.f * x) + 1.f); }
__device__ __forceinline__ unsigned pack2(short a, short b) {
    return (unsigned)(unsigned short)a | ((unsigned)(unsigned short)b << 16);
}

// Staged-vector (B-operand) column map, K=128 gates / K=128 z:
//   gate job (cols 0..127):  2u/2u+1 (u<51): h_hi/h_lo  | A: Whh_hi[n][u] both
//     102: x_hi  103: x_lo   | A: Wih_hi both
//     104: 1.0   105: 1.0    | A: bias_hi, bias_lo      | 106..127: 0
//   z job (cols 128..255): 128+2u/129+2u: c1_hi/c1_lo | A: W3_hi[g][u] both
//     230..255: 0
// N-ordering n' = u*4+g, 13 tiles; z-tile rows n' = g (0..3).
// C/D: col(lane&15)=m, row(quad*4+reg)=n' -> lane (kq,iloc) holds all 4 gates
// of unit u = nt*4+kq, batch m=iloc. Single wave => no __syncthreads at all.

__global__ void __launch_bounds__(64)
__attribute__((amdgpu_waves_per_eu(1, 1)))
lstm_sw_kernel(const float* __restrict__ input,
               const float* __restrict__ W_ih1,
               const float* __restrict__ W_hh1,
               const float* __restrict__ b_ih1,
               const float* __restrict__ b_hh1,
               const float* __restrict__ W_ih3,
               const float* __restrict__ W_hh3,
               const float* __restrict__ b_ih3,
               const float* __restrict__ b_hh3,
               float* __restrict__ out) {
    const int t = threadIdx.x;
    const int iloc = t & 15, kq = t >> 4;
    const int r0 = blockIdx.x * MROW;

    __shared__ short Hst[MROW * PAD];     // staged vector rows (single buffer)
    __shared__ float Xch[MROW * 65];      // 64-ts x chunk (row stride 65)
    __shared__ float Obuf[MROW * 64];     // c3 output chunk

    // ---- gate-tile A fragments (weights, bf16; h path compensated via cols) ----
    s16x8 Wfr[13][4];
#pragma unroll
    for (int nt = 0; nt < 13; ++nt) {
        const int np = nt * 16 + iloc;
        const int u = np >> 2, g = np & 3;
        const int n = g * H1 + u;
#pragma unroll
        for (int kt = 0; kt < 4; ++kt) {
            s16x8 bf;
#pragma unroll
            for (int j = 0; j < 8; ++j) {
                const int k = kt * 32 + kq * 8 + j;
                float v = 0.f;
                if (u < H1) {
                    if (k < 102) {
                        v = rbf(W_hh1[n * H1 + (k >> 1)]);
                    } else if (k == 102 || k == 103) {
                        v = rbf(W_ih1[n]);
                    } else if (k == 104) {
                        v = rbf(b_ih1[n] + b_hh1[n]);
                    } else if (k == 105) {
                        const float bv = b_ih1[n] + b_hh1[n];
                        v = bv - rbf(bv);
                    }
                }
                bf[j] = f2bf(v);
            }
            Wfr[nt][kt] = bf;
        }
    }
    // ---- z-tile A fragments: rows n' = g (0..3) = W_ih3[g] ----
    s16x8 Zfr[4];
#pragma unroll
    for (int kt = 0; kt < 4; ++kt) {
        s16x8 bf;
#pragma unroll
        for (int j = 0; j < 8; ++j) {
            const int kz = kt * 32 + kq * 8 + j;
            float v = 0.f;
            if (iloc < 4 && kz < 102)
                v = rbf(W_ih3[iloc * H1 + (kz >> 1)]);
            bf[j] = f2bf(v);
        }
        Zfr[kt] = bf;
    }

    const float whh3_0 = W_hh3[0], whh3_1 = W_hh3[1];
    const float whh3_2 = W_hh3[2], whh3_3 = W_hh3[3];
    const float b3_0 = b_ih3[0] + b_hh3[0];
    const float b3_1 = b_ih3[1] + b_hh3[1];
    const float b3_2 = b_ih3[2] + b_hh3[2];
    const float b3_3 = b_ih3[3] + b_hh3[3];

    // ---- LDS init (single wave: program order suffices, no barrier) ----
    for (int idx = t; idx < MROW * PAD; idx += 64) Hst[idx] = 0;
    if (t < MROW)   // cols 104/105 = 1.0 (bias multiplicand)
        *(unsigned*)&Hst[t * PAD + 104] = pack2((short)0x3F80, (short)0x3F80);

    float c1st[13];
#pragma unroll
    for (int i = 0; i < 13; ++i) c1st[i] = 0.f;
    float h3 = 0.f, c3 = 0.f;   // LSTM3 state (lanes 0..15)

#pragma unroll 1
    for (int ts = 0; ts < SEQT; ++ts) {
        // ---- stage a 64-ts x chunk ----
        if ((ts & 63) == 0) {
#pragma unroll
            for (int r = 0; r < MROW; ++r) {
                const int ci = ts + t;
                Xch[r * 65 + t] =
                    (ci < SEQT) ? input[(size_t)(r0 + r) * SEQT + ci] : 0.f;
            }
        }
        // ---- write x_t (hi/lo) into staged cols 102/103 ----
        if (t < MROW) {
            const float xv = Xch[t * 65 + (ts & 63)];
            const short xh = f2bf(xv), xl = f2bf(xv - bf2f(xh));
            *(unsigned*)&Hst[t * PAD + 102] = pack2(xh, xl);
        }

        // ---- gate B-frags (cols 0..127) ----
        s16x8 hf[4];
#pragma unroll
        for (int kt = 0; kt < 4; ++kt)
            hf[kt] = *(const s16x8*)&Hst[iloc * PAD + kt * 32 + kq * 8];

        // ---- 13 gate tiles: MFMA + lane-local epilogue ----
#pragma unroll
        for (int nt = 0; nt < 13; ++nt) {
            f32x4 acc = (f32x4){0.f, 0.f, 0.f, 0.f};
#pragma unroll
            for (int kt = 0; kt < 4; ++kt)
                acc = __builtin_amdgcn_mfma_f32_16x16x32_bf16(
                    Wfr[nt][kt], hf[kt], acc, 0, 0, 0);
            const int u = nt * 4 + kq;   // unit, batch m = iloc
            if (u < H1) {
                float c1 = c1st[nt];
                c1 = sigf(acc[1]) * c1 + sigf(acc[0]) * tanhfast(acc[2]);
                c1st[nt] = c1;
                const float h1 = sigf(acc[3]) * tanhfast(c1);
                const short hh = f2bf(h1), hl = f2bf(h1 - bf2f(hh));
                *(unsigned*)&Hst[iloc * PAD + 2 * u] = pack2(hh, hl);
                const short ch = f2bf(c1), cl = f2bf(c1 - bf2f(ch));
                *(unsigned*)&Hst[iloc * PAD + 128 + 2 * u] = pack2(ch, cl);
            }
        }

        // ---- z job (cols 128..255) + LSTM3, same ts ----
        s16x8 zf[4];
#pragma unroll
        for (int kt = 0; kt < 4; ++kt)
            zf[kt] = *(const s16x8*)&Hst[iloc * PAD + 128 + kt * 32 + kq * 8];
        f32x4 zacc = (f32x4){0.f, 0.f, 0.f, 0.f};
#pragma unroll
        for (int kt = 0; kt < 4; ++kt)
            zacc = __builtin_amdgcn_mfma_f32_16x16x32_bf16(
                Zfr[kt], zf[kt], zacc, 0, 0, 0);
        if (t < MROW) {   // lane m holds z rows g=0..3 in acc regs
            const float gi = zacc[0] + fmaf(whh3_0, h3, b3_0);
            const float gf = zacc[1] + fmaf(whh3_1, h3, b3_1);
            const float gg = zacc[2] + fmaf(whh3_2, h3, b3_2);
            const float go = zacc[3] + fmaf(whh3_3, h3, b3_3);
            c3 = sigf(gf) * c3 + sigf(gi) * tanhfast(gg);
            h3 = sigf(go) * tanhfast(c3);
            Obuf[t * 64 + (ts & 63)] = c3;
        }

        // ---- coalesced dump of a finished 64-chunk ----
        if ((ts & 63) == 63) {
            const int base = ts - 63;
#pragma unroll
            for (int r = 0; r < MROW; ++r)
                out[(size_t)(r0 + r) * SEQT + base + t] = Obuf[r * 64 + t];
        }
    }

    // tail: ts 1984..1999 (16 cols of the last chunk)
#pragma unroll
    for (int i = 0; i < 4; ++i) {
        const int idx = i * 64 + t;
        const int r = idx >> 4, c = idx & 15;
        out[(size_t)(r0 + r) * SEQT + 1984 + c] = Obuf[r * 64 + c];
    }
}

extern "C" void kernel_launch(void* const* d_in, const int* in_sizes, int n_in,
                              void* d_out, int out_size, void* d_ws, size_t ws_size,
                              hipStream_t stream) {
    const float* input = (const float*)d_in[0];
    const float* W_ih1 = (const float*)d_in[1];
    const float* W_hh1 = (const float*)d_in[2];
    const float* b_ih1 = (const float*)d_in[3];
    const float* b_hh1 = (const float*)d_in[4];
    const float* W_ih3 = (const float*)d_in[5];
    const float* W_hh3 = (const float*)d_in[6];
    const float* b_ih3 = (const float*)d_in[7];
    const float* b_hh3 = (const float*)d_in[8];
    float* out = (float*)d_out;

    lstm_sw_kernel<<<NBLK, 64, 0, stream>>>(
        input, W_ih1, W_hh1, b_ih1, b_hh1, W_ih3, W_hh3, b_ih3, b_hh3, out);
}